// Round 15
// baseline (261.689 us; speedup 1.0000x reference)
//
#include <hip/hip_runtime.h>

#define BATCH 4
#define SEQ   4096
#define DIM   1024
#define NCH   1024          // chunks per batch (SEQ/CHK)
#define CHK   4
#define NROWS (BATCH*SEQ)
#define NTG   16            // gemm K-tiles (1024/64)
#define NPAIR 8             // pairs of K-tiles

typedef __attribute__((ext_vector_type(4))) float f32x4;
typedef __attribute__((ext_vector_type(8))) short shortx8;
typedef __attribute__((ext_vector_type(4))) short shortx4;

static __device__ __forceinline__ unsigned short f2bf(float f){
    unsigned int u = __float_as_uint(f);
    u += 0x7FFFu + ((u >> 16) & 1u);
    return (unsigned short)(u >> 16);
}
static __device__ __forceinline__ float bf2f(unsigned short h){
    return __uint_as_float(((unsigned int)h) << 16);
}
static __device__ __forceinline__ float sigmoidf_fast(float x){
    return 1.0f / (1.0f + __expf(-x));
}
static __device__ __forceinline__ shortx4 pack4(f32x4 s){
    shortx4 o;
    o.x = (short)f2bf(s.x); o.y = (short)f2bf(s.y);
    o.z = (short)f2bf(s.z); o.w = (short)f2bf(s.w);
    return o;
}
static __device__ __forceinline__ shortx8 pack8(f32x4 a, f32x4 b){
    shortx8 o;
    o[0]=(short)f2bf(a.x); o[1]=(short)f2bf(a.y); o[2]=(short)f2bf(a.z); o[3]=(short)f2bf(a.w);
    o[4]=(short)f2bf(b.x); o[5]=(short)f2bf(b.y); o[6]=(short)f2bf(b.z); o[7]=(short)f2bf(b.w);
    return o;
}
static __device__ __forceinline__ f32x4 lo8(shortx8 v){
    f32x4 o; o.x=bf2f((unsigned short)v[0]); o.y=bf2f((unsigned short)v[1]);
    o.z=bf2f((unsigned short)v[2]); o.w=bf2f((unsigned short)v[3]); return o;
}
static __device__ __forceinline__ f32x4 hi8(shortx8 v){
    f32x4 o; o.x=bf2f((unsigned short)v[4]); o.y=bf2f((unsigned short)v[5]);
    o.z=bf2f((unsigned short)v[6]); o.w=bf2f((unsigned short)v[7]); return o;
}
static __device__ __forceinline__ f32x4 unpack4(shortx4 s){
    f32x4 o;
    o.x = bf2f((unsigned short)s.x); o.y = bf2f((unsigned short)s.y);
    o.z = bf2f((unsigned short)s.z); o.w = bf2f((unsigned short)s.w);
    return o;
}

// ---------------- K1: shift + decay + exp + chunk-local scan (+ fused W-pack) ----
// CHK=4: 4096 chunks -> 4.25 waves/SIMD (2x r14) to hide load+reduce latency.
__global__ __launch_bounds__(256, 4) void k_shift_scan(
    const float* __restrict__ X, const float* __restrict__ XP,
    const float* __restrict__ mu_p, const float* __restrict__ dw,
    const float* __restrict__ db_p,
    const float* __restrict__ Wr, const float* __restrict__ Wv,
    unsigned short* __restrict__ Wcat,
    unsigned short* __restrict__ shifted,
    unsigned short* __restrict__ b_local, float* __restrict__ a_local,
    float* __restrict__ cumP)
{
    const int tid  = threadIdx.x;

    if (blockIdx.x >= 1024){           // ---- weight pack path ----
        const int pb = blockIdx.x - 1024;      // 0..63
        #pragma unroll 4
        for (int i = 0; i < 32; ++i){
            const int n = pb*32 + i;
            const int grp = n >> 5, r = n & 31;
            const float* src = (r < 16) ? (Wr + (size_t)(grp*16 + r)*DIM)
                                        : (Wv + (size_t)(grp*16 + (r-16))*DIM);
            f32x4 v = reinterpret_cast<const f32x4*>(src)[tid];
            reinterpret_cast<shortx4*>(Wcat)[n*256 + tid] = pack4(v);
        }
        return;
    }

    const int lane = tid & 63;
    const int wid  = tid >> 6;
    const int cid  = blockIdx.x*4 + wid;      // 0..4095
    const int batch = cid >> 10;
    const int chunk = cid & (NCH-1);
    const int row0  = batch*SEQ + chunk*CHK;

    const float mu = mu_p[0];
    const float om = 1.0f - mu;
    const float db = db_p[0];

    const f32x4* dwv = reinterpret_cast<const f32x4*>(dw);
    const f32x4 w0 = dwv[2*lane], w1 = dwv[2*lane+1],
                w2 = dwv[128+2*lane], w3 = dwv[128+2*lane+1];

    f32x4 b0 = {0,0,0,0}, b1 = {0,0,0,0}, b2 = {0,0,0,0}, b3 = {0,0,0,0};
    float a_run = 0.f, cp = 1.f;

    const f32x4* Xv  = reinterpret_cast<const f32x4*>(X);
    const f32x4* XPv = reinterpret_cast<const f32x4*>(XP);
    shortx8* BL = reinterpret_cast<shortx8*>(b_local);
    shortx8* SH = reinterpret_cast<shortx8*>(shifted);

    #pragma unroll
    for (int r = 0; r < CHK; ++r){
        const int row = row0 + r;
        const int rb  = row*(DIM/4);          // f32x4 index
        const int rb8 = row*(DIM/8);          // shortx8 index

        f32x4 x0 = Xv[rb + 2*lane],     x1 = Xv[rb + 2*lane + 1],
              x2 = Xv[rb+128 + 2*lane], x3 = Xv[rb+128 + 2*lane + 1];
        f32x4 p0 = XPv[rb + 2*lane],     p1 = XPv[rb + 2*lane + 1],
              p2 = XPv[rb+128 + 2*lane], p3 = XPv[rb+128 + 2*lane + 1];
        f32x4 s0 = mu*x0 + om*p0, s1 = mu*x1 + om*p1;
        f32x4 s2 = mu*x2 + om*p2, s3 = mu*x3 + om*p3;

        SH[rb8 + lane]      = pack8(s0, s1);
        SH[rb8 + 64 + lane] = pack8(s2, s3);

        float dot = s0.x*w0.x + s0.y*w0.y + s0.z*w0.z + s0.w*w0.w
                  + s1.x*w1.x + s1.y*w1.y + s1.z*w1.z + s1.w*w1.w
                  + s2.x*w2.x + s2.y*w2.y + s2.z*w2.z + s2.w*w2.w
                  + s3.x*w3.x + s3.y*w3.y + s3.z*w3.z + s3.w*w3.w;

        f32x4 e0, e1, e2, e3;
        e0.x=__expf(s0.x); e0.y=__expf(s0.y); e0.z=__expf(s0.z); e0.w=__expf(s0.w);
        e1.x=__expf(s1.x); e1.y=__expf(s1.y); e1.z=__expf(s1.z); e1.w=__expf(s1.w);
        e2.x=__expf(s2.x); e2.y=__expf(s2.y); e2.z=__expf(s2.z); e2.w=__expf(s2.w);
        e3.x=__expf(s3.x); e3.y=__expf(s3.y); e3.z=__expf(s3.z); e3.w=__expf(s3.w);
        float ea = e0.x+e0.y+e0.z+e0.w + e1.x+e1.y+e1.z+e1.w
                 + e2.x+e2.y+e2.z+e2.w + e3.x+e3.y+e3.z+e3.w;

        #pragma unroll
        for (int off = 1; off < 64; off <<= 1){
            dot += __shfl_xor(dot, off, 64);
            ea  += __shfl_xor(ea,  off, 64);
        }

        const float dt = sigmoidf_fast(dot + db);
        a_run = dt*a_run + ea;
        cp   *= dt;
        b0 = dt*b0 + e0*s0;  b1 = dt*b1 + e1*s1;
        b2 = dt*b2 + e2*s2;  b3 = dt*b3 + e3*s3;

        BL[rb8 + lane]      = pack8(b0, b1);
        BL[rb8 + 64 + lane] = pack8(b2, b3);
        if (lane == 0){ a_local[row] = a_run; cumP[row] = cp; }
    }
}

// ---------------- K2: sequential carry combine (depth-16 vector prefetch) ----
// 16 blocks x 64 thr, thread owns 4 contiguous d; NCH=1024 serial chain.
__global__ __launch_bounds__(64) void k_combine(
    const unsigned short* __restrict__ b_local, const float* __restrict__ a_local,
    const float* __restrict__ cumP,
    float* __restrict__ carryA, unsigned short* __restrict__ carryB)
{
    const int batch = blockIdx.x >> 2;
    const int dseg  = blockIdx.x & 3;
    const int tid = threadIdx.x;
    const int d0 = dseg*256 + tid*4;

    __shared__ float sP[NCH], sA[NCH];
    for (int c = tid; c < NCH; c += 64){
        const int er = batch*SEQ + c*CHK + (CHK-1);
        sP[c] = cumP[er];
        sA[c] = a_local[er];
    }
    __syncthreads();

    const unsigned short* bl = b_local + (size_t)batch*SEQ*DIM + d0;
    unsigned short* cB = carryB + (size_t)batch*NCH*DIM + d0;
    const bool wA = (dseg == 0 && tid == 0);
    float* cAp = carryA + batch*NCH;

    shortx4 pf[16];
    #pragma unroll
    for (int i = 0; i < 16; ++i)
        pf[i] = *reinterpret_cast<const shortx4*>(bl + (size_t)(i*CHK + CHK-1)*DIM);

    f32x4 cb = {0,0,0,0};
    float ca = 0.f;

    for (int cc = 0; cc < NCH; cc += 16){
        const bool more = (cc + 16 < NCH);
        #pragma unroll
        for (int k = 0; k < 16; ++k){
            const int c = cc + k;
            f32x4 v = unpack4(pf[k]);
            if (more)
                pf[k] = *reinterpret_cast<const shortx4*>(bl + (size_t)((c+16)*CHK + CHK-1)*DIM);
            *reinterpret_cast<shortx4*>(cB + (size_t)c*DIM) = pack4(cb);
            if (wA) cAp[c] = ca;
            const float p = sP[c];
            cb = p*cb + v;
            ca = p*ca + sA[c];
        }
    }
}

// ---------------- K3: carry fixup + divide + LN1 -> merged (wave-per-row, 16B/lane) ----
__global__ __launch_bounds__(256) void k_fix_ln1(
    const unsigned short* __restrict__ b_local, const float* __restrict__ a_local,
    const float* __restrict__ cumP, const float* __restrict__ carryA,
    const unsigned short* __restrict__ carryB,
    const float* __restrict__ g1, const float* __restrict__ bb1,
    unsigned short* __restrict__ merged)
{
    const int tid = threadIdx.x, lane = tid & 63, wid = tid >> 6;
    const int row = blockIdx.x*4 + wid;
    const int batch = row >> 12;
    const int c = (row & (SEQ-1)) >> 2;        // CHK = 4

    const float cpv = cumP[row];
    const float a = a_local[row] + cpv * carryA[batch*NCH + c];
    const float inv_a = 1.0f / (a + 1e-8f);

    const shortx8* BL = reinterpret_cast<const shortx8*>(b_local) + (size_t)row*128;
    const shortx8* CB = reinterpret_cast<const shortx8*>(carryB) + (size_t)(batch*NCH + c)*128;

    shortx8 blA = BL[lane], blB = BL[64 + lane];
    shortx8 cbA = CB[lane], cbB = CB[64 + lane];

    f32x4 o0 = (lo8(blA) + cpv*lo8(cbA)) * inv_a;
    f32x4 o1 = (hi8(blA) + cpv*hi8(cbA)) * inv_a;
    f32x4 o2 = (lo8(blB) + cpv*lo8(cbB)) * inv_a;
    f32x4 o3 = (hi8(blB) + cpv*hi8(cbB)) * inv_a;

    float s  = o0.x+o0.y+o0.z+o0.w + o1.x+o1.y+o1.z+o1.w
             + o2.x+o2.y+o2.z+o2.w + o3.x+o3.y+o3.z+o3.w;
    float s2 = o0.x*o0.x+o0.y*o0.y+o0.z*o0.z+o0.w*o0.w
             + o1.x*o1.x+o1.y*o1.y+o1.z*o1.z+o1.w*o1.w
             + o2.x*o2.x+o2.y*o2.y+o2.z*o2.z+o2.w*o2.w
             + o3.x*o3.x+o3.y*o3.y+o3.z*o3.z+o3.w*o3.w;
    #pragma unroll
    for (int off = 1; off < 64; off <<= 1){
        s  += __shfl_xor(s,  off, 64);
        s2 += __shfl_xor(s2, off, 64);
    }
    const float mean = s * (1.0f/DIM);
    const float rstd = rsqrtf(s2*(1.0f/DIM) - mean*mean + 1e-5f);

    const f32x4* G = reinterpret_cast<const f32x4*>(g1);
    const f32x4* Bb = reinterpret_cast<const f32x4*>(bb1);
    f32x4 m0 = (o0 - mean)*rstd*G[2*lane]       + Bb[2*lane];
    f32x4 m1 = (o1 - mean)*rstd*G[2*lane+1]     + Bb[2*lane+1];
    f32x4 m2 = (o2 - mean)*rstd*G[128+2*lane]   + Bb[128+2*lane];
    f32x4 m3 = (o3 - mean)*rstd*G[128+2*lane+1] + Bb[128+2*lane+1];

    shortx8* MG = reinterpret_cast<shortx8*>(merged) + (size_t)row*128;
    MG[lane]      = pack8(m0, m1);
    MG[64 + lane] = pack8(m2, m3);
}

// ---------------- K5: 256x256 bf16 GEMM — ring-10 (r8 best: 72.9us) ----------
typedef __attribute__((address_space(3))) unsigned int lds_uint;
typedef __attribute__((address_space(1))) unsigned int glob_uint;
static __device__ __forceinline__ void gload16(const unsigned short* g, char* l){
    __builtin_amdgcn_global_load_lds((const glob_uint*)g, (lds_uint*)l, 16, 0, 0);
}
#define SBAR() do { __builtin_amdgcn_sched_barrier(0); __builtin_amdgcn_s_barrier(); __builtin_amdgcn_sched_barrier(0); } while(0)
#define LGKM0() do { asm volatile("s_waitcnt lgkmcnt(0)" ::: "memory"); __builtin_amdgcn_sched_barrier(0); } while(0)
#define VMC(n)  do { asm volatile("s_waitcnt vmcnt(" #n ")" ::: "memory"); __builtin_amdgcn_sched_barrier(0); } while(0)
#define LDSE 136

__global__ __launch_bounds__(512, 2) void k_gemm(
    const unsigned short* __restrict__ A,    // merged bf16 [16384][1024]
    const unsigned short* __restrict__ Bt,   // Wcat  bf16 [2048][1024]
    const float* __restrict__ rbias, const float* __restrict__ vbias,
    unsigned short* __restrict__ gv)         // bf16 [16384][1024]
{
    __shared__ __align__(16) char lds[163840];   // 10 x 16KB ring
    const int tid  = threadIdx.x;
    const int lane = tid & 63;
    const int wid  = tid >> 6;
    const int wqm  = wid >> 2;       // 0..1
    const int wqn  = wid & 3;        // 0..3

    const int bid  = blockIdx.x;
    const int wgid = (bid & 7)*64 + (bid >> 3);
    const int mt = wgid >> 3, nt = wgid & 7;
    const int m0 = mt*256, n0 = nt*256;

    // staging source (pre-swizzled col-group)
    const int rin = lane >> 2;
    const int scg = (lane & 3) ^ (((lane >> 5) & 1) << 1);
    const unsigned short* gA = A  + (size_t)(m0 + wid*16 + rin)*DIM + scg*8;
    const unsigned short* gB = Bt + (size_t)(n0 + wid*16 + rin)*DIM + scg*8;

    // fragment read offset (matching swizzle)
    const int fr = lane & 15, fq = lane >> 4;
    const int soff = fr*64 + ((fq*16) ^ ((fr & 8) ? 32 : 0));

    f32x4 acc0[8], acc1[8], acc2[8], acc3[8];
    #pragma unroll
    for (int i = 0; i < 8; ++i){
        acc0[i] = (f32x4){0,0,0,0}; acc1[i] = (f32x4){0,0,0,0};
        acc2[i] = (f32x4){0,0,0,0}; acc3[i] = (f32x4){0,0,0,0};
    }

    auto STAGE_P = [&](int k){
        if (k >= 4*NTG) return;
        const int T = k >> 2, pc = k & 3, slot = k % 10;
        const int isA = (pc == 0 || pc == 3);
        const int h   = (pc >= 2) ? 1 : 0;
        char* dst = lds + slot*16384 + wid*2048;
        const unsigned short* s = (isA ? gA : gB) + (size_t)(h*128)*DIM + T*64;
        gload16(s,      dst);
        gload16(s + 32, dst + 1024);
    };

    shortx8 aA[8], bB0[4], bB1[4];
    auto LOAD_A = [&](int slot){
        const char* base = lds + slot*16384;
        #pragma unroll
        for (int rf = 0; rf < 4; ++rf)
            #pragma unroll
            for (int kb = 0; kb < 2; ++kb)
                aA[rf*2+kb] = *reinterpret_cast<const shortx8*>(
                    base + (wqm*4 + rf)*2048 + kb*1024 + soff);
    };
    auto LOAD_B = [&](int slot, shortx8* dst){
        const char* base = lds + slot*16384;
        #pragma unroll
        for (int cf = 0; cf < 2; ++cf)
            #pragma unroll
            for (int kb = 0; kb < 2; ++kb)
                dst[cf*2+kb] = *reinterpret_cast<const shortx8*>(
                    base + (wqn*2 + cf)*2048 + kb*1024 + soff);
    };

    #define MFMA16(ACC, BX)                                                     \
        __builtin_amdgcn_s_setprio(1);                                          \
        _Pragma("unroll")                                                       \
        for (int rf = 0; rf < 4; ++rf)                                          \
            _Pragma("unroll")                                                   \
            for (int cf = 0; cf < 2; ++cf){                                     \
                ACC[rf*2+cf] = __builtin_amdgcn_mfma_f32_16x16x32_bf16(         \
                    aA[rf*2+0], BX[cf*2+0], ACC[rf*2+cf], 0,0,0);               \
                ACC[rf*2+cf] = __builtin_amdgcn_mfma_f32_16x16x32_bf16(         \
                    aA[rf*2+1], BX[cf*2+1], ACC[rf*2+cf], 0,0,0);               \
            }                                                                   \
        __builtin_amdgcn_s_setprio(0);

    #pragma unroll
    for (int k = 0; k < 8; ++k) STAGE_P(k);
    VMC(6);
    SBAR();

    for (int i = 0; i < NPAIR; ++i){
        const int T0 = 2*i;
        const int sA0t0 = (4*T0  ) % 10, sB0t0 = (4*T0+1) % 10;
        const int sB1t0 = (4*T0+2) % 10, sA1t0 = (4*T0+3) % 10;
        const int sA0t1 = (4*T0+4) % 10, sB0t1 = (4*T0+5) % 10;
        const int sB1t1 = (4*T0+6) % 10, sA1t1 = (4*T0+7) % 10;
        const int P = 8*i;
        const bool last = (i == NPAIR-1);

        // p0
        LOAD_A(sA0t0); LOAD_B(sB0t0, bB0);
        STAGE_P(P + 8);
        LGKM0();
        MFMA16(acc0, bB0);
        SBAR();
        // p1
        LOAD_B(sB1t0, bB1);
        STAGE_P(P + 9);
        LGKM0();
        MFMA16(acc1, bB1);
        SBAR();
        // p2
        LOAD_A(sA1t0);
        STAGE_P(P + 10);
        LGKM0();
        MFMA16(acc3, bB1);
        SBAR();
        // p3 — counted vmcnt
        STAGE_P(P + 11);
        if (last) { VMC(0); } else { VMC(6); }
        MFMA16(acc2, bB0);
        SBAR();
        // p4
        LOAD_A(sA0t1); LOAD_B(sB0t1, bB0);
        STAGE_P(P + 12);
        LGKM0();
        MFMA16(acc0, bB0);
        SBAR();
        // p5
        LOAD_B(sB1t1, bB1);
        STAGE_P(P + 13);
        LGKM0();
        MFMA16(acc1, bB1);
        SBAR();
        // p6
        LOAD_A(sA1t1);
        STAGE_P(P + 14);
        LGKM0();
        MFMA16(acc3, bB1);
        SBAR();
        // p7 — counted vmcnt
        STAGE_P(P + 15);
        if (!last) { VMC(6); }
        MFMA16(acc2, bB0);
        SBAR();
    }

    // ---- epilogue: sigmoid(gate)*value -> padded LDS transpose -> store ----
    __syncthreads();
    unsigned short* ep = reinterpret_cast<unsigned short*>(lds);  // [256][LDSE]
    #pragma unroll
    for (int q = 0; q < 4; ++q){
        const f32x4* ac = (q==0) ? acc0 : (q==1) ? acc1 : (q==2) ? acc2 : acc3;
        const int QM = q >> 1, QN = q & 1;
        const int el = QN*64 + wqn*16 + fr;            // 0..127
        const float rbe = rbias[nt*128 + el];
        const float vbe = vbias[nt*128 + el];
        #pragma unroll
        for (int rf = 0; rf < 4; ++rf){
            const int rbase = QM*128 + wqm*64 + rf*16 + fq*4;
            f32x4 ga = ac[rf*2+0], va = ac[rf*2+1];
            #pragma unroll
            for (int qq = 0; qq < 4; ++qq){
                const float g = sigmoidf_fast(ga[qq] + rbe);
                ep[(rbase + qq)*LDSE + el] = f2bf(g*(va[qq] + vbe));
            }
        }
    }
    __syncthreads();
    #pragma unroll
    for (int p = 0; p < 8; ++p){
        const int r  = p*32 + (tid >> 4);
        const int c8 = tid & 15;
        shortx8 val = *reinterpret_cast<const shortx8*>(&ep[r*LDSE + c8*8]);
        *reinterpret_cast<shortx8*>(&gv[(size_t)(m0 + r)*DIM + nt*128 + c8*8]) = val;
    }
    #undef MFMA16
}

// ---------------- K6: LN2 + residual (wave-per-row, 16B/lane) ----------------
__global__ __launch_bounds__(256) void k_ln2_res(
    const unsigned short* __restrict__ gvb, const unsigned short* __restrict__ shifted,
    const float* __restrict__ g2, const float* __restrict__ b2,
    float* __restrict__ out)
{
    const int tid = threadIdx.x, lane = tid & 63, wid = tid >> 6;
    const int row = blockIdx.x*4 + wid;

    const shortx8* GV = reinterpret_cast<const shortx8*>(gvb) + (size_t)row*128;
    const shortx8* SH = reinterpret_cast<const shortx8*>(shifted) + (size_t)row*128;

    shortx8 gvA = GV[lane], gvB = GV[64 + lane];
    f32x4 v0 = lo8(gvA), v1 = hi8(gvA), v2 = lo8(gvB), v3 = hi8(gvB);

    float s  = v0.x+v0.y+v0.z+v0.w + v1.x+v1.y+v1.z+v1.w
             + v2.x+v2.y+v2.z+v2.w + v3.x+v3.y+v3.z+v3.w;
    float s2 = v0.x*v0.x+v0.y*v0.y+v0.z*v0.z+v0.w*v0.w
             + v1.x*v1.x+v1.y*v1.y+v1.z*v1.z+v1.w*v1.w
             + v2.x*v2.x+v2.y*v2.y+v2.z*v2.z+v2.w*v2.w
             + v3.x*v3.x+v3.y*v3.y+v3.z*v3.z+v3.w*v3.w;
    #pragma unroll
    for (int off = 1; off < 64; off <<= 1){
        s  += __shfl_xor(s,  off, 64);
        s2 += __shfl_xor(s2, off, 64);
    }
    const float mean = s * (1.0f/DIM);
    const float rstd = rsqrtf(s2*(1.0f/DIM) - mean*mean + 1e-5f);

    shortx8 shA = SH[lane], shB = SH[64 + lane];
    const f32x4* G = reinterpret_cast<const f32x4*>(g2);
    const f32x4* Bb = reinterpret_cast<const f32x4*>(b2);

    f32x4 o0 = lo8(shA) + (v0 - mean)*rstd*G[2*lane]       + Bb[2*lane];
    f32x4 o1 = hi8(shA) + (v1 - mean)*rstd*G[2*lane+1]     + Bb[2*lane+1];
    f32x4 o2 = lo8(shB) + (v2 - mean)*rstd*G[128+2*lane]   + Bb[128+2*lane];
    f32x4 o3 = hi8(shB) + (v3 - mean)*rstd*G[128+2*lane+1] + Bb[128+2*lane+1];

    f32x4* O = reinterpret_cast<f32x4*>(out) + (size_t)row*256;
    O[2*lane]       = o0;
    O[2*lane+1]     = o1;
    O[128+2*lane]   = o2;
    O[128+2*lane+1] = o3;
}

extern "C" void kernel_launch(void* const* d_in, const int* in_sizes, int n_in,
                              void* d_out, int out_size, void* d_ws, size_t ws_size,
                              hipStream_t stream)
{
    (void)in_sizes; (void)n_in; (void)out_size; (void)ws_size;
    const float* x     = (const float*)d_in[0];
    const float* xprev = (const float*)d_in[1];
    const float* mu    = (const float*)d_in[2];
    const float* dw    = (const float*)d_in[3];
    const float* db    = (const float*)d_in[4];
    const float* ln1g  = (const float*)d_in[5];
    const float* ln1b  = (const float*)d_in[6];
    const float* Wr    = (const float*)d_in[7];
    const float* Wrb   = (const float*)d_in[8];
    const float* Wv    = (const float*)d_in[9];
    const float* Wvb   = (const float*)d_in[10];
    const float* ln2g  = (const float*)d_in[11];
    const float* ln2b  = (const float*)d_in[12];
    float* out = (float*)d_out;

    char* ws = (char*)d_ws;
    size_t off = 0;
    auto alloc = [&](size_t bytes) -> void* {
        void* p = ws + off;
        off += (bytes + 255) & ~(size_t)255;
        return p;
    };
    unsigned short* shifted = (unsigned short*)alloc((size_t)NROWS*DIM*2);
    unsigned short* b_local = (unsigned short*)alloc((size_t)NROWS*DIM*2);
    unsigned short* merged  = (unsigned short*)alloc((size_t)NROWS*DIM*2);
    unsigned short* carryB  = (unsigned short*)alloc((size_t)BATCH*NCH*DIM*2);
    unsigned short* Wcat    = (unsigned short*)alloc((size_t)2048*1024*2);
    float* a_local          = (float*)alloc((size_t)NROWS*4);
    float* cumP             = (float*)alloc((size_t)NROWS*4);
    float* carryA           = (float*)alloc((size_t)BATCH*NCH*4);
    unsigned short* gvbuf   = b_local;   // b_local dead after k_fix_ln1

    hipLaunchKernelGGL(k_shift_scan, dim3(1088), dim3(256), 0, stream,
                       x, xprev, mu, dw, db, Wr, Wv, Wcat, shifted, b_local, a_local, cumP);
    hipLaunchKernelGGL(k_combine,    dim3(16),   dim3(64),  0, stream,
                       b_local, a_local, cumP, carryA, carryB);
    hipLaunchKernelGGL(k_fix_ln1,    dim3(4096), dim3(256), 0, stream,
                       b_local, a_local, cumP, carryA, carryB, ln1g, ln1b, merged);
    hipLaunchKernelGGL(k_gemm,       dim3(512),  dim3(512), 0, stream,
                       merged, Wcat, Wrb, Wvb, gvbuf);
    hipLaunchKernelGGL(k_ln2_res,    dim3(4096), dim3(256), 0, stream,
                       gvbuf, shifted, ln2g, ln2b, out);
}

// Round 16
// 206.835 us; speedup vs baseline: 1.2652x; 1.2652x over previous
//
#include <hip/hip_runtime.h>

#define BATCH 4
#define SEQ   4096
#define DIM   1024
#define NCH   512
#define CHK   8
#define NROWS (BATCH*SEQ)
#define NTG   16            // gemm K-tiles (1024/64)
#define NPAIR 8             // pairs of K-tiles

typedef __attribute__((ext_vector_type(4))) float f32x4;
typedef __attribute__((ext_vector_type(8))) short shortx8;
typedef __attribute__((ext_vector_type(4))) short shortx4;

static __device__ __forceinline__ unsigned short f2bf(float f){
    unsigned int u = __float_as_uint(f);
    u += 0x7FFFu + ((u >> 16) & 1u);
    return (unsigned short)(u >> 16);
}
static __device__ __forceinline__ float bf2f(unsigned short h){
    return __uint_as_float(((unsigned int)h) << 16);
}
static __device__ __forceinline__ float sigmoidf_fast(float x){
    return 1.0f / (1.0f + __expf(-x));
}
static __device__ __forceinline__ shortx4 pack4(f32x4 s){
    shortx4 o;
    o.x = (short)f2bf(s.x); o.y = (short)f2bf(s.y);
    o.z = (short)f2bf(s.z); o.w = (short)f2bf(s.w);
    return o;
}
static __device__ __forceinline__ shortx8 pack8(f32x4 a, f32x4 b){
    shortx8 o;
    o[0]=(short)f2bf(a.x); o[1]=(short)f2bf(a.y); o[2]=(short)f2bf(a.z); o[3]=(short)f2bf(a.w);
    o[4]=(short)f2bf(b.x); o[5]=(short)f2bf(b.y); o[6]=(short)f2bf(b.z); o[7]=(short)f2bf(b.w);
    return o;
}
static __device__ __forceinline__ f32x4 lo8(shortx8 v){
    f32x4 o; o.x=bf2f((unsigned short)v[0]); o.y=bf2f((unsigned short)v[1]);
    o.z=bf2f((unsigned short)v[2]); o.w=bf2f((unsigned short)v[3]); return o;
}
static __device__ __forceinline__ f32x4 hi8(shortx8 v){
    f32x4 o; o.x=bf2f((unsigned short)v[4]); o.y=bf2f((unsigned short)v[5]);
    o.z=bf2f((unsigned short)v[6]); o.w=bf2f((unsigned short)v[7]); return o;
}
static __device__ __forceinline__ f32x4 unpack4(shortx4 s){
    f32x4 o;
    o.x = bf2f((unsigned short)s.x); o.y = bf2f((unsigned short)s.y);
    o.z = bf2f((unsigned short)s.z); o.w = bf2f((unsigned short)s.w);
    return o;
}

// ---------------- K1: shift + decay + exp + chunk-local scan (+ fused W-pack) ----
// lane owns bf16 groups [lane*8,+8) and [512+lane*8,+8): all bf16 stores 16B/lane.
__global__ __launch_bounds__(256) void k_shift_scan(
    const float* __restrict__ X, const float* __restrict__ XP,
    const float* __restrict__ mu_p, const float* __restrict__ dw,
    const float* __restrict__ db_p,
    const float* __restrict__ Wr, const float* __restrict__ Wv,
    unsigned short* __restrict__ Wcat,
    unsigned short* __restrict__ shifted,
    unsigned short* __restrict__ b_local, float* __restrict__ a_local,
    float* __restrict__ cumP)
{
    const int tid  = threadIdx.x;

    if (blockIdx.x >= 512){            // ---- weight pack path ----
        const int pb = blockIdx.x - 512;       // 0..63
        #pragma unroll 4
        for (int i = 0; i < 32; ++i){
            const int n = pb*32 + i;
            const int grp = n >> 5, r = n & 31;
            const float* src = (r < 16) ? (Wr + (size_t)(grp*16 + r)*DIM)
                                        : (Wv + (size_t)(grp*16 + (r-16))*DIM);
            f32x4 v = reinterpret_cast<const f32x4*>(src)[tid];
            reinterpret_cast<shortx4*>(Wcat)[n*256 + tid] = pack4(v);
        }
        return;
    }

    const int lane = tid & 63;
    const int wid  = tid >> 6;
    const int cid  = blockIdx.x*4 + wid;
    const int batch = cid >> 9;
    const int chunk = cid & (NCH-1);
    const int row0  = batch*SEQ + chunk*CHK;

    const float mu = mu_p[0];
    const float om = 1.0f - mu;
    const float db = db_p[0];

    const f32x4* dwv = reinterpret_cast<const f32x4*>(dw);
    const f32x4 w0 = dwv[2*lane], w1 = dwv[2*lane+1],
                w2 = dwv[128+2*lane], w3 = dwv[128+2*lane+1];

    f32x4 b0 = {0,0,0,0}, b1 = {0,0,0,0}, b2 = {0,0,0,0}, b3 = {0,0,0,0};
    float a_run = 0.f, cp = 1.f;

    const f32x4* Xv  = reinterpret_cast<const f32x4*>(X);
    const f32x4* XPv = reinterpret_cast<const f32x4*>(XP);
    shortx8* BL = reinterpret_cast<shortx8*>(b_local);
    shortx8* SH = reinterpret_cast<shortx8*>(shifted);

    for (int r = 0; r < CHK; ++r){
        const int row = row0 + r;
        const int rb  = row*(DIM/4);          // f32x4 index
        const int rb8 = row*(DIM/8);          // shortx8 index

        f32x4 x0 = Xv[rb + 2*lane],     x1 = Xv[rb + 2*lane + 1],
              x2 = Xv[rb+128 + 2*lane], x3 = Xv[rb+128 + 2*lane + 1];
        f32x4 p0 = XPv[rb + 2*lane],     p1 = XPv[rb + 2*lane + 1],
              p2 = XPv[rb+128 + 2*lane], p3 = XPv[rb+128 + 2*lane + 1];
        f32x4 s0 = mu*x0 + om*p0, s1 = mu*x1 + om*p1;
        f32x4 s2 = mu*x2 + om*p2, s3 = mu*x3 + om*p3;

        SH[rb8 + lane]      = pack8(s0, s1);
        SH[rb8 + 64 + lane] = pack8(s2, s3);

        float dot = s0.x*w0.x + s0.y*w0.y + s0.z*w0.z + s0.w*w0.w
                  + s1.x*w1.x + s1.y*w1.y + s1.z*w1.z + s1.w*w1.w
                  + s2.x*w2.x + s2.y*w2.y + s2.z*w2.z + s2.w*w2.w
                  + s3.x*w3.x + s3.y*w3.y + s3.z*w3.z + s3.w*w3.w;

        f32x4 e0, e1, e2, e3;
        e0.x=__expf(s0.x); e0.y=__expf(s0.y); e0.z=__expf(s0.z); e0.w=__expf(s0.w);
        e1.x=__expf(s1.x); e1.y=__expf(s1.y); e1.z=__expf(s1.z); e1.w=__expf(s1.w);
        e2.x=__expf(s2.x); e2.y=__expf(s2.y); e2.z=__expf(s2.z); e2.w=__expf(s2.w);
        e3.x=__expf(s3.x); e3.y=__expf(s3.y); e3.z=__expf(s3.z); e3.w=__expf(s3.w);
        float ea = e0.x+e0.y+e0.z+e0.w + e1.x+e1.y+e1.z+e1.w
                 + e2.x+e2.y+e2.z+e2.w + e3.x+e3.y+e3.z+e3.w;

        #pragma unroll
        for (int off = 1; off < 64; off <<= 1){
            dot += __shfl_xor(dot, off, 64);
            ea  += __shfl_xor(ea,  off, 64);
        }

        const float dt = sigmoidf_fast(dot + db);
        a_run = dt*a_run + ea;
        cp   *= dt;
        b0 = dt*b0 + e0*s0;  b1 = dt*b1 + e1*s1;
        b2 = dt*b2 + e2*s2;  b3 = dt*b3 + e3*s3;

        BL[rb8 + lane]      = pack8(b0, b1);
        BL[rb8 + 64 + lane] = pack8(b2, b3);
        if (lane == 0){ a_local[row] = a_run; cumP[row] = cp; }
    }
}

// ---------------- K2: sequential carry combine (depth-16 vector prefetch) ----
__global__ __launch_bounds__(64) void k_combine(
    const unsigned short* __restrict__ b_local, const float* __restrict__ a_local,
    const float* __restrict__ cumP,
    float* __restrict__ carryA, unsigned short* __restrict__ carryB)
{
    const int batch = blockIdx.x >> 2;
    const int dseg  = blockIdx.x & 3;
    const int tid = threadIdx.x;
    const int d0 = dseg*256 + tid*4;

    __shared__ float sP[NCH], sA[NCH];
    for (int c = tid; c < NCH; c += 64){
        const int er = batch*SEQ + c*CHK + (CHK-1);
        sP[c] = cumP[er];
        sA[c] = a_local[er];
    }
    __syncthreads();

    const unsigned short* bl = b_local + (size_t)batch*SEQ*DIM + d0;
    unsigned short* cB = carryB + (size_t)batch*NCH*DIM + d0;
    const bool wA = (dseg == 0 && tid == 0);
    float* cAp = carryA + batch*NCH;

    shortx4 pf[16];
    #pragma unroll
    for (int i = 0; i < 16; ++i)
        pf[i] = *reinterpret_cast<const shortx4*>(bl + (i*CHK + CHK-1)*DIM);

    f32x4 cb = {0,0,0,0};
    float ca = 0.f;

    for (int cc = 0; cc < NCH; cc += 16){
        const bool more = (cc + 16 < NCH);
        #pragma unroll
        for (int k = 0; k < 16; ++k){
            const int c = cc + k;
            f32x4 v = unpack4(pf[k]);
            if (more)
                pf[k] = *reinterpret_cast<const shortx4*>(bl + ((c+16)*CHK + CHK-1)*DIM);
            *reinterpret_cast<shortx4*>(cB + (size_t)c*DIM) = pack4(cb);
            if (wA) cAp[c] = ca;
            const float p = sP[c];
            cb = p*cb + v;
            ca = p*ca + sA[c];
        }
    }
}

// ---------------- K3: carry fixup + divide + LN1 -> merged (wave-per-row, 16B/lane) ----
__global__ __launch_bounds__(256) void k_fix_ln1(
    const unsigned short* __restrict__ b_local, const float* __restrict__ a_local,
    const float* __restrict__ cumP, const float* __restrict__ carryA,
    const unsigned short* __restrict__ carryB,
    const float* __restrict__ g1, const float* __restrict__ bb1,
    unsigned short* __restrict__ merged)
{
    const int tid = threadIdx.x, lane = tid & 63, wid = tid >> 6;
    const int row = blockIdx.x*4 + wid;
    const int batch = row >> 12;
    const int c = (row & (SEQ-1)) >> 3;        // CHK = 8

    const float cpv = cumP[row];
    const float a = a_local[row] + cpv * carryA[batch*NCH + c];
    const float inv_a = 1.0f / (a + 1e-8f);

    const shortx8* BL = reinterpret_cast<const shortx8*>(b_local) + (size_t)row*128;
    const shortx8* CB = reinterpret_cast<const shortx8*>(carryB) + (size_t)(batch*NCH + c)*128;

    shortx8 blA = BL[lane], blB = BL[64 + lane];
    shortx8 cbA = CB[lane], cbB = CB[64 + lane];

    f32x4 o0 = (lo8(blA) + cpv*lo8(cbA)) * inv_a;
    f32x4 o1 = (hi8(blA) + cpv*hi8(cbA)) * inv_a;
    f32x4 o2 = (lo8(blB) + cpv*lo8(cbB)) * inv_a;
    f32x4 o3 = (hi8(blB) + cpv*hi8(cbB)) * inv_a;

    float s  = o0.x+o0.y+o0.z+o0.w + o1.x+o1.y+o1.z+o1.w
             + o2.x+o2.y+o2.z+o2.w + o3.x+o3.y+o3.z+o3.w;
    float s2 = o0.x*o0.x+o0.y*o0.y+o0.z*o0.z+o0.w*o0.w
             + o1.x*o1.x+o1.y*o1.y+o1.z*o1.z+o1.w*o1.w
             + o2.x*o2.x+o2.y*o2.y+o2.z*o2.z+o2.w*o2.w
             + o3.x*o3.x+o3.y*o3.y+o3.z*o3.z+o3.w*o3.w;
    #pragma unroll
    for (int off = 1; off < 64; off <<= 1){
        s  += __shfl_xor(s,  off, 64);
        s2 += __shfl_xor(s2, off, 64);
    }
    const float mean = s * (1.0f/DIM);
    const float rstd = rsqrtf(s2*(1.0f/DIM) - mean*mean + 1e-5f);

    const f32x4* G = reinterpret_cast<const f32x4*>(g1);
    const f32x4* Bb = reinterpret_cast<const f32x4*>(bb1);
    f32x4 m0 = (o0 - mean)*rstd*G[2*lane]       + Bb[2*lane];
    f32x4 m1 = (o1 - mean)*rstd*G[2*lane+1]     + Bb[2*lane+1];
    f32x4 m2 = (o2 - mean)*rstd*G[128+2*lane]   + Bb[128+2*lane];
    f32x4 m3 = (o3 - mean)*rstd*G[128+2*lane+1] + Bb[128+2*lane+1];

    shortx8* MG = reinterpret_cast<shortx8*>(merged) + (size_t)row*128;
    MG[lane]      = pack8(m0, m1);
    MG[64 + lane] = pack8(m2, m3);
}

// ---------------- K5: 256x256 bf16 GEMM — ring-10 (r8 best: 72.9us) ----------
typedef __attribute__((address_space(3))) unsigned int lds_uint;
typedef __attribute__((address_space(1))) unsigned int glob_uint;
static __device__ __forceinline__ void gload16(const unsigned short* g, char* l){
    __builtin_amdgcn_global_load_lds((const glob_uint*)g, (lds_uint*)l, 16, 0, 0);
}
#define SBAR() do { __builtin_amdgcn_sched_barrier(0); __builtin_amdgcn_s_barrier(); __builtin_amdgcn_sched_barrier(0); } while(0)
#define LGKM0() do { asm volatile("s_waitcnt lgkmcnt(0)" ::: "memory"); __builtin_amdgcn_sched_barrier(0); } while(0)
#define VMC(n)  do { asm volatile("s_waitcnt vmcnt(" #n ")" ::: "memory"); __builtin_amdgcn_sched_barrier(0); } while(0)
#define LDSE 136

__global__ __launch_bounds__(512, 2) void k_gemm(
    const unsigned short* __restrict__ A,    // merged bf16 [16384][1024]
    const unsigned short* __restrict__ Bt,   // Wcat  bf16 [2048][1024]
    const float* __restrict__ rbias, const float* __restrict__ vbias,
    unsigned short* __restrict__ gv)         // bf16 [16384][1024]
{
    __shared__ __align__(16) char lds[163840];   // 10 x 16KB ring
    const int tid  = threadIdx.x;
    const int lane = tid & 63;
    const int wid  = tid >> 6;
    const int wqm  = wid >> 2;       // 0..1
    const int wqn  = wid & 3;        // 0..3

    const int bid  = blockIdx.x;
    const int wgid = (bid & 7)*64 + (bid >> 3);
    const int mt = wgid >> 3, nt = wgid & 7;
    const int m0 = mt*256, n0 = nt*256;

    // staging source (pre-swizzled col-group)
    const int rin = lane >> 2;
    const int scg = (lane & 3) ^ (((lane >> 5) & 1) << 1);
    const unsigned short* gA = A  + (size_t)(m0 + wid*16 + rin)*DIM + scg*8;
    const unsigned short* gB = Bt + (size_t)(n0 + wid*16 + rin)*DIM + scg*8;

    // fragment read offset (matching swizzle)
    const int fr = lane & 15, fq = lane >> 4;
    const int soff = fr*64 + ((fq*16) ^ ((fr & 8) ? 32 : 0));

    f32x4 acc0[8], acc1[8], acc2[8], acc3[8];
    #pragma unroll
    for (int i = 0; i < 8; ++i){
        acc0[i] = (f32x4){0,0,0,0}; acc1[i] = (f32x4){0,0,0,0};
        acc2[i] = (f32x4){0,0,0,0}; acc3[i] = (f32x4){0,0,0,0};
    }

    auto STAGE_P = [&](int k){
        if (k >= 4*NTG) return;
        const int T = k >> 2, pc = k & 3, slot = k % 10;
        const int isA = (pc == 0 || pc == 3);
        const int h   = (pc >= 2) ? 1 : 0;
        char* dst = lds + slot*16384 + wid*2048;
        const unsigned short* s = (isA ? gA : gB) + (size_t)(h*128)*DIM + T*64;
        gload16(s,      dst);
        gload16(s + 32, dst + 1024);
    };

    shortx8 aA[8], bB0[4], bB1[4];
    auto LOAD_A = [&](int slot){
        const char* base = lds + slot*16384;
        #pragma unroll
        for (int rf = 0; rf < 4; ++rf)
            #pragma unroll
            for (int kb = 0; kb < 2; ++kb)
                aA[rf*2+kb] = *reinterpret_cast<const shortx8*>(
                    base + (wqm*4 + rf)*2048 + kb*1024 + soff);
    };
    auto LOAD_B = [&](int slot, shortx8* dst){
        const char* base = lds + slot*16384;
        #pragma unroll
        for (int cf = 0; cf < 2; ++cf)
            #pragma unroll
            for (int kb = 0; kb < 2; ++kb)
                dst[cf*2+kb] = *reinterpret_cast<const shortx8*>(
                    base + (wqn*2 + cf)*2048 + kb*1024 + soff);
    };

    #define MFMA16(ACC, BX)                                                     \
        __builtin_amdgcn_s_setprio(1);                                          \
        _Pragma("unroll")                                                       \
        for (int rf = 0; rf < 4; ++rf)                                          \
            _Pragma("unroll")                                                   \
            for (int cf = 0; cf < 2; ++cf){                                     \
                ACC[rf*2+cf] = __builtin_amdgcn_mfma_f32_16x16x32_bf16(         \
                    aA[rf*2+0], BX[cf*2+0], ACC[rf*2+cf], 0,0,0);               \
                ACC[rf*2+cf] = __builtin_amdgcn_mfma_f32_16x16x32_bf16(         \
                    aA[rf*2+1], BX[cf*2+1], ACC[rf*2+cf], 0,0,0);               \
            }                                                                   \
        __builtin_amdgcn_s_setprio(0);

    #pragma unroll
    for (int k = 0; k < 8; ++k) STAGE_P(k);
    VMC(6);
    SBAR();

    for (int i = 0; i < NPAIR; ++i){
        const int T0 = 2*i;
        const int sA0t0 = (4*T0  ) % 10, sB0t0 = (4*T0+1) % 10;
        const int sB1t0 = (4*T0+2) % 10, sA1t0 = (4*T0+3) % 10;
        const int sA0t1 = (4*T0+4) % 10, sB0t1 = (4*T0+5) % 10;
        const int sB1t1 = (4*T0+6) % 10, sA1t1 = (4*T0+7) % 10;
        const int P = 8*i;
        const bool last = (i == NPAIR-1);

        // p0
        LOAD_A(sA0t0); LOAD_B(sB0t0, bB0);
        STAGE_P(P + 8);
        LGKM0();
        MFMA16(acc0, bB0);
        SBAR();
        // p1
        LOAD_B(sB1t0, bB1);
        STAGE_P(P + 9);
        LGKM0();
        MFMA16(acc1, bB1);
        SBAR();
        // p2
        LOAD_A(sA1t0);
        STAGE_P(P + 10);
        LGKM0();
        MFMA16(acc3, bB1);
        SBAR();
        // p3 — counted vmcnt
        STAGE_P(P + 11);
        if (last) { VMC(0); } else { VMC(6); }
        MFMA16(acc2, bB0);
        SBAR();
        // p4
        LOAD_A(sA0t1); LOAD_B(sB0t1, bB0);
        STAGE_P(P + 12);
        LGKM0();
        MFMA16(acc0, bB0);
        SBAR();
        // p5
        LOAD_B(sB1t1, bB1);
        STAGE_P(P + 13);
        LGKM0();
        MFMA16(acc1, bB1);
        SBAR();
        // p6
        LOAD_A(sA1t1);
        STAGE_P(P + 14);
        LGKM0();
        MFMA16(acc3, bB1);
        SBAR();
        // p7 — counted vmcnt
        STAGE_P(P + 15);
        if (!last) { VMC(6); }
        MFMA16(acc2, bB0);
        SBAR();
    }

    // ---- epilogue: sigmoid(gate)*value -> padded LDS transpose -> store ----
    __syncthreads();
    unsigned short* ep = reinterpret_cast<unsigned short*>(lds);  // [256][LDSE]
    #pragma unroll
    for (int q = 0; q < 4; ++q){
        const f32x4* ac = (q==0) ? acc0 : (q==1) ? acc1 : (q==2) ? acc2 : acc3;
        const int QM = q >> 1, QN = q & 1;
        const int el = QN*64 + wqn*16 + fr;            // 0..127
        const float rbe = rbias[nt*128 + el];
        const float vbe = vbias[nt*128 + el];
        #pragma unroll
        for (int rf = 0; rf < 4; ++rf){
            const int rbase = QM*128 + wqm*64 + rf*16 + fq*4;
            f32x4 ga = ac[rf*2+0], va = ac[rf*2+1];
            #pragma unroll
            for (int qq = 0; qq < 4; ++qq){
                const float g = sigmoidf_fast(ga[qq] + rbe);
                ep[(rbase + qq)*LDSE + el] = f2bf(g*(va[qq] + vbe));
            }
        }
    }
    __syncthreads();
    #pragma unroll
    for (int p = 0; p < 8; ++p){
        const int r  = p*32 + (tid >> 4);
        const int c8 = tid & 15;
        shortx8 val = *reinterpret_cast<const shortx8*>(&ep[r*LDSE + c8*8]);
        *reinterpret_cast<shortx8*>(&gv[(size_t)(m0 + r)*DIM + nt*128 + c8*8]) = val;
    }
    #undef MFMA16
}

// ---------------- K6: LN2 + residual (wave-per-row, 16B/lane) ----------------
__global__ __launch_bounds__(256) void k_ln2_res(
    const unsigned short* __restrict__ gvb, const unsigned short* __restrict__ shifted,
    const float* __restrict__ g2, const float* __restrict__ b2,
    float* __restrict__ out)
{
    const int tid = threadIdx.x, lane = tid & 63, wid = tid >> 6;
    const int row = blockIdx.x*4 + wid;

    const shortx8* GV = reinterpret_cast<const shortx8*>(gvb) + (size_t)row*128;
    const shortx8* SH = reinterpret_cast<const shortx8*>(shifted) + (size_t)row*128;

    shortx8 gvA = GV[lane], gvB = GV[64 + lane];
    f32x4 v0 = lo8(gvA), v1 = hi8(gvA), v2 = lo8(gvB), v3 = hi8(gvB);

    float s  = v0.x+v0.y+v0.z+v0.w + v1.x+v1.y+v1.z+v1.w
             + v2.x+v2.y+v2.z+v2.w + v3.x+v3.y+v3.z+v3.w;
    float s2 = v0.x*v0.x+v0.y*v0.y+v0.z*v0.z+v0.w*v0.w
             + v1.x*v1.x+v1.y*v1.y+v1.z*v1.z+v1.w*v1.w
             + v2.x*v2.x+v2.y*v2.y+v2.z*v2.z+v2.w*v2.w
             + v3.x*v3.x+v3.y*v3.y+v3.z*v3.z+v3.w*v3.w;
    #pragma unroll
    for (int off = 1; off < 64; off <<= 1){
        s  += __shfl_xor(s,  off, 64);
        s2 += __shfl_xor(s2, off, 64);
    }
    const float mean = s * (1.0f/DIM);
    const float rstd = rsqrtf(s2*(1.0f/DIM) - mean*mean + 1e-5f);

    shortx8 shA = SH[lane], shB = SH[64 + lane];
    const f32x4* G = reinterpret_cast<const f32x4*>(g2);
    const f32x4* Bb = reinterpret_cast<const f32x4*>(b2);

    f32x4 o0 = lo8(shA) + (v0 - mean)*rstd*G[2*lane]       + Bb[2*lane];
    f32x4 o1 = hi8(shA) + (v1 - mean)*rstd*G[2*lane+1]     + Bb[2*lane+1];
    f32x4 o2 = lo8(shB) + (v2 - mean)*rstd*G[128+2*lane]   + Bb[128+2*lane];
    f32x4 o3 = hi8(shB) + (v3 - mean)*rstd*G[128+2*lane+1] + Bb[128+2*lane+1];

    f32x4* O = reinterpret_cast<f32x4*>(out) + (size_t)row*256;
    O[2*lane]       = o0;
    O[2*lane+1]     = o1;
    O[128+2*lane]   = o2;
    O[128+2*lane+1] = o3;
}

extern "C" void kernel_launch(void* const* d_in, const int* in_sizes, int n_in,
                              void* d_out, int out_size, void* d_ws, size_t ws_size,
                              hipStream_t stream)
{
    (void)in_sizes; (void)n_in; (void)out_size; (void)ws_size;
    const float* x     = (const float*)d_in[0];
    const float* xprev = (const float*)d_in[1];
    const float* mu    = (const float*)d_in[2];
    const float* dw    = (const float*)d_in[3];
    const float* db    = (const float*)d_in[4];
    const float* ln1g  = (const float*)d_in[5];
    const float* ln1b  = (const float*)d_in[6];
    const float* Wr    = (const float*)d_in[7];
    const float* Wrb   = (const float*)d_in[8];
    const float* Wv    = (const float*)d_in[9];
    const float* Wvb   = (const float*)d_in[10];
    const float* ln2g  = (const float*)d_in[11];
    const float* ln2b  = (const float*)d_in[12];
    float* out = (float*)d_out;

    char* ws = (char*)d_ws;
    size_t off = 0;
    auto alloc = [&](size_t bytes) -> void* {
        void* p = ws + off;
        off += (bytes + 255) & ~(size_t)255;
        return p;
    };
    unsigned short* shifted = (unsigned short*)alloc((size_t)NROWS*DIM*2);
    unsigned short* b_local = (unsigned short*)alloc((size_t)NROWS*DIM*2);
    unsigned short* merged  = (unsigned short*)alloc((size_t)NROWS*DIM*2);
    unsigned short* carryB  = (unsigned short*)alloc((size_t)BATCH*NCH*DIM*2);
    unsigned short* Wcat    = (unsigned short*)alloc((size_t)2048*1024*2);
    float* a_local          = (float*)alloc((size_t)NROWS*4);
    float* cumP             = (float*)alloc((size_t)NROWS*4);
    float* carryA           = (float*)alloc((size_t)BATCH*NCH*4);
    unsigned short* gvbuf   = b_local;   // b_local dead after k_fix_ln1

    hipLaunchKernelGGL(k_shift_scan, dim3(576),  dim3(256), 0, stream,
                       x, xprev, mu, dw, db, Wr, Wv, Wcat, shifted, b_local, a_local, cumP);
    hipLaunchKernelGGL(k_combine,    dim3(16),   dim3(64),  0, stream,
                       b_local, a_local, cumP, carryA, carryB);
    hipLaunchKernelGGL(k_fix_ln1,    dim3(4096), dim3(256), 0, stream,
                       b_local, a_local, cumP, carryA, carryB, ln1g, ln1b, merged);
    hipLaunchKernelGGL(k_gemm,       dim3(512),  dim3(512), 0, stream,
                       merged, Wcat, Wrb, Wvb, gvbuf);
    hipLaunchKernelGGL(k_ln2_res,    dim3(4096), dim3(256), 0, stream,
                       gvbuf, shifted, ln2g, ln2b, out);
}